// Round 13
// baseline (103.962 us; speedup 1.0000x reference)
//
#include <hip/hip_runtime.h>
#include <cstdint>

#define IN_F   4096
#define OUT_F  14336
#define GROUP  128
#define KROT   8
#define BATCH  16
#define NJP    1792           // packed words per weight row
#define NG     32             // quant groups
#define NKC    8              // K-chunks (one group per wave)

typedef __attribute__((ext_vector_type(8))) short short8;  // 8 bf16
typedef __attribute__((ext_vector_type(4))) float f32x4;

// Module-scope scratch (no d_ws dependence).
__device__ uint32_t g_xa[BATCH * IN_F / 2];      // rotated activations, bf16 pairs
__device__ float    g_rs[NG * BATCH];            // per-(group,row) sums of bf16 acts
__device__ float    g_part[NKC * BATCH * OUT_F]; // 8 K-chunk fp32 partials (7.3 MB)

static __device__ __forceinline__ unsigned short f2bf(float f) {
    union { float f; uint32_t i; } v; v.f = f;
    uint32_t u = v.i;
    uint32_t r = u + 0x7FFFu + ((u >> 16) & 1u);  // RNE
    return (unsigned short)(r >> 16);
}
static __device__ __forceinline__ float bf2f(uint32_t u16) {
    union { uint32_t i; float f; } v; v.i = u16 << 16; return v.f;
}

// ---------------------------------------------------------------------------
// Kernel 1: rotation layers + bf16 pack + per-group row-sums (verified R8).
// ---------------------------------------------------------------------------
__global__ __launch_bounds__(1024) void k_rotate(
    const float* __restrict__ x,      // [16][4096] f32 (fp16 promoted)
    const float* __restrict__ theta,  // [8][2048]  f32
    const int*   __restrict__ pairs,  // [8][4096]  int32
    const float* __restrict__ cscale) // [4096]     f32
{
    __shared__ float row[IN_F];
    const int b   = blockIdx.x;
    const int tid = threadIdx.x;

    int2  ij0[KROT], ij1[KROT];
    float c0[KROT], s0[KROT], c1[KROT], s1[KROT];
#pragma unroll
    for (int k = 0; k < KROT; ++k) {
        const int2*  pk = (const int2*)(pairs + k * IN_F);
        const float* tk = theta + k * (IN_F / 2);
        ij0[k] = pk[tid];
        ij1[k] = pk[tid + 1024];
        __sincosf(tk[tid],        &s0[k], &c0[k]);
        __sincosf(tk[tid + 1024], &s1[k], &c1[k]);
    }

    for (int i = tid; i < IN_F; i += 1024) row[i] = x[b * IN_F + i];
    __syncthreads();

#pragma unroll
    for (int k = 0; k < KROT; ++k) {
        float a0 = row[ij0[k].x], b0 = row[ij0[k].y];
        float a1 = row[ij1[k].x], b1 = row[ij1[k].y];
        row[ij0[k].x] = c0[k] * a0 - s0[k] * b0;
        row[ij0[k].y] = s0[k] * a0 + c0[k] * b0;
        row[ij1[k].x] = c1[k] * a1 - s1[k] * b1;
        row[ij1[k].y] = s1[k] * a1 + c1[k] * b1;
        __syncthreads();
    }

    float p0, p1;
    {
        int i = tid;
        uint32_t lo = f2bf(row[2 * i]     * cscale[2 * i]);
        uint32_t hi = f2bf(row[2 * i + 1] * cscale[2 * i + 1]);
        g_xa[b * (IN_F / 2) + i] = lo | (hi << 16);
        p0 = bf2f(lo) + bf2f(hi);
        i = tid + 1024;
        lo = f2bf(row[2 * i]     * cscale[2 * i]);
        hi = f2bf(row[2 * i + 1] * cscale[2 * i + 1]);
        g_xa[b * (IN_F / 2) + i] = lo | (hi << 16);
        p1 = bf2f(lo) + bf2f(hi);
    }
#pragma unroll
    for (int m = 1; m < 64; m <<= 1) {
        p0 += __shfl_xor(p0, m, 64);
        p1 += __shfl_xor(p1, m, 64);
    }
    if ((tid & 63) == 0) {
        const int w = tid >> 6;
        g_rs[w * BATCH + b]        = p0;
        g_rs[(16 + w) * BATCH + b] = p1;
    }
}

// ---------------------------------------------------------------------------
// Kernel 2: MFMA dequant-GEMM, 8-way K-split. Grid 112 n-slices x 8 K-chunks
// = 896 blocks -> 4 blocks/CU (launch_bounds(256,4)) = 4 waves/SIMD: doubles
// memory parallelism vs R12's 2 (k_gemm was latency-hiding-bound at ~3 TB/s
// effective fetch). Each wave owns exactly ONE quant group -> single fold at
// the end (m[] accumulators and the thrice-proven-neutral prefetch deleted;
// VGPR drops so the occupancy cap binds on grid, not registers).
// Barrier-free main loop (R10, verified); plain-store epilogue (R11's fence
// epilogue measured catastrophic).
// ---------------------------------------------------------------------------
__global__ __launch_bounds__(256, 4) void k_gemm(
    const int*   __restrict__ qweight, // [4096][1792] int32
    const int*   __restrict__ qzeros,  // [32][1792]   int32
    const float* __restrict__ scales)  // [32][14336]  f32
{
    __shared__ uint4 ldsb[4 * 512];    // 4 wave-private 8KB regions (32 KB)

    const int tid  = threadIdx.x;
    const int bn   = blockIdx.x % 112;
    const int bk   = blockIdx.x / 112;    // K-chunk 0..7
    const int n0   = bn * 128;
    const int jp0  = bn * 16;             // 16 packed words per block row
    const int w    = tid >> 6;            // wave 0..3
    const int lane = tid & 63;
    const int jp   = lane & 15;           // staging word 0..15
    const int rr   = lane >> 4;           // staging k-octet 0..3
    const int mrow = lane & 15;           // MFMA m-row / n-col lane
    const int quad = lane >> 4;

    uint4* ldsw = ldsb + w * 512;

    const int gg     = bk * 4 + w;        // this wave's quant group (0..31)
    const int kbase0 = gg * GROUP;

    // ---- prologue: hoist per-n-tile scales / zero-terms / rowsum ----------
    float sv[8], tv[8];
    f32x4 rsv;
    {
        const int sh = 4 * (mrow & 7);
        rsv = *(const f32x4*)(g_rs + gg * BATCH + quad * 4);
#pragma unroll
        for (int t = 0; t < 8; ++t) {
            const int col = n0 + t * 16 + mrow;
            const float s = scales[(size_t)gg * OUT_F + col];
            const float z = 128.0f +
                (float)(((uint32_t)qzeros[gg * NJP + (col >> 3)] >> sh) & 15u);
            sv[t] = s;
            tv[t] = s * z;
        }
    }

    f32x4 ga[8];
#pragma unroll
    for (int t = 0; t < 8; ++t) ga[t] = (f32x4){0.f, 0.f, 0.f, 0.f};

#pragma unroll
    for (int it = 0; it < 4; ++it) {      // 4 sub-chunks of 32 k
        const int kb = kbase0 + it * 32 + rr * 8;

        uint32_t wc[8];
#pragma unroll
        for (int i = 0; i < 8; ++i)
            wc[i] = (uint32_t)qweight[(size_t)(kb + i) * NJP + jp0 + jp];

        union { uint4 q; short8 s; } af;
        af.q = *(const uint4*)(g_xa + mrow * (IN_F / 2)
                               + ((kbase0 + it * 32) >> 1) + quad * 4);

        // dequant: bf16(128+v) bit-OR; bank-spread col permutation
#pragma unroll
        for (int cc = 0; cc < 8; ++cc) {
            const int c  = cc ^ (jp & 7);
            const int sh = 4 * c;
            uint4 cell;
            uint32_t pk[4];
#pragma unroll
            for (int h = 0; h < 4; ++h) {
                uint32_t lo = (wc[2 * h]     >> sh) & 15u;
                uint32_t hi = (wc[2 * h + 1] >> sh) & 15u;
                pk[h] = 0x43004300u | lo | (hi << 16);
            }
            cell.x = pk[0]; cell.y = pk[1]; cell.z = pk[2]; cell.w = pk[3];
            ldsw[rr * 128 + jp * 8 + c] = cell;   // [k-octet][col]
        }

        // wave-synchronous MFMA: 8 n-tiles, 1 k-tile
#pragma unroll
        for (int t = 0; t < 8; ++t) {
            union { uint4 q; short8 s; } bf;
            bf.q = ldsw[quad * 128 + t * 16 + mrow];
            ga[t] = __builtin_amdgcn_mfma_f32_16x16x32_bf16(af.s, bf.s, ga[t], 0, 0, 0);
        }
    }

    // ---- single fold: result = s*ga - (s*(128+iz))*rowsum -----------------
    // ---- epilogue: cross-wave reduction in LDS, plain coalesced store -----
    float* fw = (float*)ldsb + w * 2048;   // [row 16][col 128]
#pragma unroll
    for (int t = 0; t < 8; ++t)
#pragma unroll
        for (int r = 0; r < 4; ++r)
            fw[(quad * 4 + r) * 128 + t * 16 + mrow] =
                fmaf(sv[t], ga[t][r], -tv[t] * rsv[r]);
    __syncthreads();

    const float* fb   = (const float*)ldsb;
    const int    colg = (tid & 31) * 4;    // 0..124
    const int    row  = tid >> 5;          // 0..7 (rows row and row+8)
    f32x4 sA = {0.f, 0.f, 0.f, 0.f}, sB = {0.f, 0.f, 0.f, 0.f};
#pragma unroll
    for (int ww = 0; ww < 4; ++ww) {
        sA += *(const f32x4*)(fb + ww * 2048 + row * 128 + colg);
        sB += *(const f32x4*)(fb + ww * 2048 + (row + 8) * 128 + colg);
    }
    float* pp = g_part + (size_t)bk * BATCH * OUT_F + n0 + colg;
    *(f32x4*)(pp + (size_t)row * OUT_F)       = sA;
    *(f32x4*)(pp + (size_t)(row + 8) * OUT_F) = sB;
}

// ---------------------------------------------------------------------------
// Kernel 3: sum the 8 K-chunk partials -> d_out. float4 per thread.
// ---------------------------------------------------------------------------
__global__ __launch_bounds__(128) void k_reduce(float* __restrict__ out)
{
    const int t = blockIdx.x * 128 + threadIdx.x;   // 0..57343
    const size_t j = (size_t)t * 4;
    f32x4 s = {0.f, 0.f, 0.f, 0.f};
#pragma unroll
    for (int kc = 0; kc < NKC; ++kc)
        s += *(const f32x4*)(g_part + (size_t)kc * BATCH * OUT_F + j);
    *(f32x4*)(out + j) = s;
}

extern "C" void kernel_launch(void* const* d_in, const int* in_sizes, int n_in,
                              void* d_out, int out_size, void* d_ws, size_t ws_size,
                              hipStream_t stream) {
    const float* x       = (const float*)d_in[0];
    const float* theta   = (const float*)d_in[1];
    const int*   pairs   = (const int*)d_in[2];
    const float* cscale  = (const float*)d_in[3];
    const int*   qweight = (const int*)d_in[4];
    const int*   qzeros  = (const int*)d_in[5];
    const float* scales  = (const float*)d_in[6];
    float*       out     = (float*)d_out;
    (void)d_ws; (void)ws_size;

    k_rotate<<<16, 1024, 0, stream>>>(x, theta, pairs, cscale);
    k_gemm<<<112 * NKC, 256, 0, stream>>>(qweight, qzeros, scales);
    k_reduce<<<(BATCH * OUT_F) / (128 * 4), 128, 0, stream>>>(out);
}